// Round 11
// baseline (1224.602 us; speedup 1.0000x reference)
//
#include <hip/hip_runtime.h>
#include <cstdint>
#include <cstddef>

#define FDIM 128
#define CHUNK 4096   // edges per binning chunk
#define BSHIFT 8     // 256 nodes per bucket
#define BMASK 255
#define MAXB 512     // max buckets supported (N <= 131072)
#define GRIDB 1024   // mega-kernel grid: 256 CU x 4 blocks/CU (exact residency)

typedef unsigned short ushort_t;
typedef __attribute__((ext_vector_type(8))) short short8;   // 8 bf16 (4 VGPRs)
typedef __attribute__((ext_vector_type(4))) float floatx4;  // MFMA C/D

// bf16 helpers (bit-level, RTN-even).
__device__ inline ushort_t f2bf(float f) {
  unsigned u = __float_as_uint(f);
  u += 0x7fffu + ((u >> 16) & 1u);
  return (ushort_t)(u >> 16);
}
__device__ inline float bf2f(ushort_t h) {
  return __uint_as_float((unsigned)h << 16);
}

// ---------------- front kernel: mm1 (x@W1) + hist + W-prep + zero --------
// R18: launch overhead is the #2 cost; mm1 has no dep on the CSR build so
// it rides the hist launch. Blocks [0,mmb)=mm1 w/ inline W1 conversion;
// [mmb,mmb+nch)=chunk hist; +0=W2 prep & counter; +1=W3 prep; +2=zero.
__global__ __launch_bounds__(256) void k_front(
    const float* __restrict__ x, const float* __restrict__ W1,
    const float* __restrict__ W2, const float* __restrict__ W3,
    ushort_t* __restrict__ h0, int n, int mmb,
    const int* __restrict__ dst, int e, int nb,
    int* __restrict__ chunkHist, int nch,
    ushort_t* __restrict__ wsw, int* __restrict__ counter,
    float* __restrict__ partials_g, int g_count, int* __restrict__ bar) {
  __shared__ ushort_t Bs[16384];  // 32 KB (hist path aliases first 2 KB)
  int tid = threadIdx.x;
  int bid = blockIdx.x;
  if (bid >= mmb) {
    int r = bid - mmb;
    if (r < nch) {  // per-chunk dst-bucket histogram (R14: keep bucketed)
      int* h = (int*)Bs;
      int base = r * CHUNK;
      int end = min(base + CHUNK, e);
      for (int i = tid; i < nb; i += 256) h[i] = 0;
      __syncthreads();
      for (int i = base + tid; i < end; i += 256)
        atomicAdd(&h[dst[i] >> BSHIFT], 1);
      __syncthreads();
      for (int b = tid; b < nb; b += 256)
        chunkHist[(size_t)r * nb + b] = h[b];
      return;
    }
    int b = r - nch;
    if (b == 2) {  // zero boundary-pool accumulator + mega grid-barrier state
      for (int i = tid; i < g_count * FDIM; i += 256) partials_g[i] = 0.f;
      if (tid < 64) bar[tid] = 0;
      return;
    }
    if (b == 0 && tid == 0) *counter = 0;  // for scan1's atomic bump
    // W prep (W2,W3): fp32 -> bf16, B-fragment order (slot (ct,lane&15)
    // holds TRUE column (lane&15)*8+ct -> coalesced uint4 C-stores).
    const float* W = (b == 0) ? W2 : W3;
    ushort_t* o = wsw + (size_t)b * 16384;
    for (int idx = tid; idx < 16384; idx += 256) {
      int j = idx & 7;
      int lane = (idx >> 3) & 63;
      int ct = (idx >> 9) & 7;
      int kc = idx >> 12;
      int k = kc * 32 + (lane >> 4) * 8 + j;
      int col = (lane & 15) * 8 + ct;
      o[idx] = f2bf(W[k * FDIM + col]);
    }
    return;
  }
  // ---- mm1: fp32 x @ W1 -> h0 bf16; W1 converted inline during staging.
  for (int q = tid; q < 2048; q += 256) {
    int lane = q & 63;
    int ct = (q >> 6) & 7;
    int kc = q >> 9;
    int col = (lane & 15) * 8 + ct;
    int kb = kc * 32 + (lane >> 4) * 8;
    unsigned t0 = f2bf(W1[(kb + 0) * FDIM + col]);
    unsigned t1 = f2bf(W1[(kb + 1) * FDIM + col]);
    unsigned t2 = f2bf(W1[(kb + 2) * FDIM + col]);
    unsigned t3 = f2bf(W1[(kb + 3) * FDIM + col]);
    unsigned t4 = f2bf(W1[(kb + 4) * FDIM + col]);
    unsigned t5 = f2bf(W1[(kb + 5) * FDIM + col]);
    unsigned t6 = f2bf(W1[(kb + 6) * FDIM + col]);
    unsigned t7 = f2bf(W1[(kb + 7) * FDIM + col]);
    uint4 pk;
    pk.x = t0 | (t1 << 16);
    pk.y = t2 | (t3 << 16);
    pk.z = t4 | (t5 << 16);
    pk.w = t6 | (t7 << 16);
    ((uint4*)Bs)[q] = pk;
  }
  __syncthreads();

  int w = tid >> 6;
  int lane = tid & 63;
  int quad = lane >> 4;
  int l15 = lane & 15;
  int rb = bid * 128 + w * 32;
  int row0 = rb + l15;
  int row1 = rb + 16 + l15;
  bool v0 = row0 < n, v1 = row1 < n;

  floatx4 acc[2][8];
#pragma unroll
  for (int rt = 0; rt < 2; ++rt)
#pragma unroll
    for (int ct = 0; ct < 8; ++ct) acc[rt][ct] = floatx4{0.f, 0.f, 0.f, 0.f};

#pragma unroll
  for (int kc = 0; kc < 4; ++kc) {
    int k0 = kc * 32 + quad * 8;
    short8 a0 = short8{0, 0, 0, 0, 0, 0, 0, 0};
    short8 a1 = short8{0, 0, 0, 0, 0, 0, 0, 0};
    if (v0) {
      float4 f0 = *(const float4*)&x[(size_t)row0 * FDIM + k0];
      float4 f1 = *(const float4*)&x[(size_t)row0 * FDIM + k0 + 4];
      a0 = short8{(short)f2bf(f0.x), (short)f2bf(f0.y), (short)f2bf(f0.z),
                  (short)f2bf(f0.w), (short)f2bf(f1.x), (short)f2bf(f1.y),
                  (short)f2bf(f1.z), (short)f2bf(f1.w)};
    }
    if (v1) {
      float4 f0 = *(const float4*)&x[(size_t)row1 * FDIM + k0];
      float4 f1 = *(const float4*)&x[(size_t)row1 * FDIM + k0 + 4];
      a1 = short8{(short)f2bf(f0.x), (short)f2bf(f0.y), (short)f2bf(f0.z),
                  (short)f2bf(f0.w), (short)f2bf(f1.x), (short)f2bf(f1.y),
                  (short)f2bf(f1.z), (short)f2bf(f1.w)};
    }
#pragma unroll
    for (int ct = 0; ct < 8; ++ct) {
      short8 bf = *(const short8*)&Bs[((kc * 8 + ct) * 64 + lane) * 8];
      acc[0][ct] = __builtin_amdgcn_mfma_f32_16x16x32_bf16(a0, bf, acc[0][ct], 0, 0, 0);
      acc[1][ct] = __builtin_amdgcn_mfma_f32_16x16x32_bf16(a1, bf, acc[1][ct], 0, 0, 0);
    }
  }
#pragma unroll
  for (int rt = 0; rt < 2; ++rt) {
#pragma unroll
    for (int i = 0; i < 4; ++i) {
      int row = rb + rt * 16 + quad * 4 + i;
      if (row < n) {
        uint4 pk;
        pk.x = (unsigned)f2bf(acc[rt][0][i]) | ((unsigned)f2bf(acc[rt][1][i]) << 16);
        pk.y = (unsigned)f2bf(acc[rt][2][i]) | ((unsigned)f2bf(acc[rt][3][i]) << 16);
        pk.z = (unsigned)f2bf(acc[rt][4][i]) | ((unsigned)f2bf(acc[rt][5][i]) << 16);
        pk.w = (unsigned)f2bf(acc[rt][6][i]) | ((unsigned)f2bf(acc[rt][7][i]) << 16);
        *(uint4*)&h0[(size_t)row * FDIM + l15 * 8] = pk;
      }
    }
  }
}

// Per-bucket scan over the chunk axis; bucket base atomic-bump allocated
// (disjoint segments, order-free -- validated R10).
__global__ __launch_bounds__(512) void k_scan1(const int* __restrict__ chunkHist,
                                               int nchunks, int nb,
                                               int* __restrict__ chunkOff,
                                               int* __restrict__ bucketTotal,
                                               int* __restrict__ bucketBase,
                                               int* __restrict__ counter) {
  __shared__ int sb[512];
  int b = blockIdx.x;
  int t = threadIdx.x;
  int base = 0;
  for (int c0 = 0; c0 < nchunks; c0 += 512) {
    int c = c0 + t;
    int v = (c < nchunks) ? chunkHist[(size_t)c * nb + b] : 0;
    int x = v;
    sb[t] = x;
    __syncthreads();
    for (int off = 1; off < 512; off <<= 1) {
      int y = (t >= off) ? sb[t - off] : 0;
      __syncthreads();
      x += y;
      sb[t] = x;
      __syncthreads();
    }
    if (c < nchunks) chunkOff[(size_t)c * nb + b] = base + x - v;
    int tileTot = sb[511];
    __syncthreads();
    base += tileTot;
  }
  if (t == 0) {
    bucketTotal[b] = base;
    bucketBase[b] = atomicAdd(counter, base);
  }
}

__global__ __launch_bounds__(256) void k_bin(const int* __restrict__ src,
                                             const int* __restrict__ dst, int e, int nb,
                                             const int* __restrict__ chunkHist,
                                             const int* __restrict__ chunkOff,
                                             const int* __restrict__ bucketBase,
                                             unsigned* __restrict__ binned) {
  __shared__ unsigned sortedL[CHUNK];
  __shared__ int gtarget[CHUNK];
  __shared__ int lbase[MAXB], lcur[MAXB], gbase[MAXB];
  __shared__ int stmp[256];
  int c = blockIdx.x;
  int base = c * CHUNK;
  int end = min(base + CHUNK, e);
  for (int i = threadIdx.x; i < nb; i += 256) {
    lbase[i] = chunkHist[(size_t)c * nb + i];  // temp: counts
    gbase[i] = bucketBase[i] + chunkOff[(size_t)c * nb + i];
  }
  __syncthreads();
  int carry = 0;
  for (int i0 = 0; i0 < nb; i0 += 256) {
    int i = i0 + threadIdx.x;
    int v = (i < nb) ? lbase[i] : 0;
    int x = v;
    stmp[threadIdx.x] = x;
    __syncthreads();
    for (int off = 1; off < 256; off <<= 1) {
      int y = (threadIdx.x >= off) ? stmp[threadIdx.x - off] : 0;
      __syncthreads();
      x += y;
      stmp[threadIdx.x] = x;
      __syncthreads();
    }
    if (i < nb) lbase[i] = carry + x - v;
    int tileTot = stmp[255];
    __syncthreads();
    carry += tileTot;
  }
  for (int i = threadIdx.x; i < nb; i += 256) lcur[i] = lbase[i];
  __syncthreads();
  for (int i = base + threadIdx.x; i < end; i += 256) {
    int d = dst[i];
    int sv = src[i];
    int b = d >> BSHIFT;
    int slot = atomicAdd(&lcur[b], 1);
    sortedL[slot] = ((unsigned)sv << BSHIFT) | (unsigned)(d & BMASK);
    gtarget[slot] = gbase[b] + (slot - lbase[b]);
  }
  __syncthreads();
  for (int i = threadIdx.x; i < end - base; i += 256)
    binned[gtarget[i]] = sortedL[i];
}

// One block per bucket: per-node CSR rows in the bucket's private window.
// colPacked = pure src here; the mega P1 EDGW rider ORs in bf16(dis)<<17.
__global__ __launch_bounds__(256) void k_fill2(const unsigned* __restrict__ binned,
                                               const int* __restrict__ bucketBase,
                                               const int* __restrict__ bucketTotal,
                                               int n,
                                               int* __restrict__ rowStart,
                                               int* __restrict__ deg,
                                               float* __restrict__ dis,
                                               unsigned* __restrict__ colPacked) {
  __shared__ int h[256], sb[256], cur[256];
  int b = blockIdx.x;
  int s0 = bucketBase[b], s1 = s0 + bucketTotal[b];
  int nodeBase = b << BSHIFT;
  int t = threadIdx.x;
  h[t] = 0;
  __syncthreads();
  for (int i = s0 + t; i < s1; i += 256) atomicAdd(&h[binned[i] & BMASK], 1);
  __syncthreads();
  int v = h[t];
  int x = v;
  sb[t] = x;
  __syncthreads();
  for (int off = 1; off < 256; off <<= 1) {
    int y = (t >= off) ? sb[t - off] : 0;
    __syncthreads();
    x += y;
    sb[t] = x;
    __syncthreads();
  }
  int start = s0 + x - v;
  cur[t] = start;
  int node = nodeBase + t;
  if (node < n) {
    rowStart[node] = start;
    deg[node] = v;
    dis[node] = rsqrtf((float)(v + 1));  // +1 self-loop
  }
  __syncthreads();
  for (int i = s0 + t; i < s1; i += 256) {
    unsigned en = binned[i];
    int slot = atomicAdd(&cur[en & BMASK], 1);
    colPacked[slot] = en >> BSHIFT;  // pure src (< 2^17)
  }
}

// ---------------- mega-kernel phase bodies --------------------------------

// R20: device grid barrier, 32-leaf atomic tree (R16: 1024 serialized RMWs
// on one line would cost ~7us; tree is ~0.5us). Agent-scope fences provide
// the cross-XCD L2 writeback/invalidate a kernel boundary would. Bounded
// spin: a residency bug becomes a wrong answer, not a hang.
__device__ __forceinline__ void grid_sync(int* bar, int nblk, int expect, int bid) {
  __syncthreads();
  if (threadIdx.x == 0) {
    __threadfence();  // release: publish this block's writes device-wide
    int leaf = bid & 31;
    int lo = __hip_atomic_fetch_add(&bar[leaf], 1, __ATOMIC_RELAXED,
                                    __HIP_MEMORY_SCOPE_AGENT);
    if (lo == (nblk >> 5) - 1) {  // last arrival at this leaf
      __hip_atomic_store(&bar[leaf], 0, __ATOMIC_RELAXED, __HIP_MEMORY_SCOPE_AGENT);
      int ro = __hip_atomic_fetch_add(&bar[32], 1, __ATOMIC_RELAXED,
                                      __HIP_MEMORY_SCOPE_AGENT);
      if (ro == 31) {  // last leaf: flip generation
        __hip_atomic_store(&bar[32], 0, __ATOMIC_RELAXED, __HIP_MEMORY_SCOPE_AGENT);
        __hip_atomic_fetch_add(&bar[33], 1, __ATOMIC_RELEASE,
                               __HIP_MEMORY_SCOPE_AGENT);
      }
    }
    int guard = 0;
    while (__hip_atomic_load(&bar[33], __ATOMIC_ACQUIRE,
                             __HIP_MEMORY_SCOPE_AGENT) < expect &&
           guard < (1 << 25)) {
      __builtin_amdgcn_s_sleep(4);
      ++guard;
    }
    __threadfence();  // acquire: invalidate stale L1/L2 before phase reads
  }
  __syncthreads();
}

__device__ __forceinline__ void edgw_body(int rb, int tid,
                                          unsigned* __restrict__ colPacked,
                                          const float* __restrict__ dis, int e) {
  int base = rb * 2048 + tid;
#pragma unroll
  for (int k = 0; k < 8; ++k) {
    int i = base + k * 256;
    if (i < e) {
      unsigned p = colPacked[i] & 0x1ffffu;
      colPacked[i] = p | ((unsigned)f2bf(dis[p]) << 17);
    }
  }
}

__device__ __forceinline__ void mm_body(int vb, int tid,
                                        const ushort_t* __restrict__ Ain,
                                        const ushort_t* __restrict__ Wsw,
                                        ushort_t* __restrict__ O, int n,
                                        ushort_t* Bs) {
  for (int q = tid; q < 2048; q += 256)
    ((uint4*)Bs)[q] = ((const uint4*)Wsw)[q];
  __syncthreads();
  int w = tid >> 6;
  int lane = tid & 63;
  int quad = lane >> 4;
  int l15 = lane & 15;
  int rb = vb * 128 + w * 32;
  int row0 = rb + l15;
  int row1 = rb + 16 + l15;
  bool v0 = row0 < n, v1 = row1 < n;
  floatx4 acc[2][8];
#pragma unroll
  for (int rt = 0; rt < 2; ++rt)
#pragma unroll
    for (int ct = 0; ct < 8; ++ct) acc[rt][ct] = floatx4{0.f, 0.f, 0.f, 0.f};
#pragma unroll
  for (int kc = 0; kc < 4; ++kc) {
    int k0 = kc * 32 + quad * 8;
    short8 a0 = short8{0, 0, 0, 0, 0, 0, 0, 0};
    short8 a1 = short8{0, 0, 0, 0, 0, 0, 0, 0};
    if (v0) a0 = *(const short8*)&Ain[(size_t)row0 * FDIM + k0];
    if (v1) a1 = *(const short8*)&Ain[(size_t)row1 * FDIM + k0];
#pragma unroll
    for (int ct = 0; ct < 8; ++ct) {
      short8 bf = *(const short8*)&Bs[((kc * 8 + ct) * 64 + lane) * 8];
      acc[0][ct] = __builtin_amdgcn_mfma_f32_16x16x32_bf16(a0, bf, acc[0][ct], 0, 0, 0);
      acc[1][ct] = __builtin_amdgcn_mfma_f32_16x16x32_bf16(a1, bf, acc[1][ct], 0, 0, 0);
    }
  }
#pragma unroll
  for (int rt = 0; rt < 2; ++rt) {
#pragma unroll
    for (int i = 0; i < 4; ++i) {
      int row = rb + rt * 16 + quad * 4 + i;
      if (row < n) {
        uint4 pk;
        pk.x = (unsigned)f2bf(acc[rt][0][i]) | ((unsigned)f2bf(acc[rt][1][i]) << 16);
        pk.y = (unsigned)f2bf(acc[rt][2][i]) | ((unsigned)f2bf(acc[rt][3][i]) << 16);
        pk.z = (unsigned)f2bf(acc[rt][4][i]) | ((unsigned)f2bf(acc[rt][5][i]) << 16);
        pk.w = (unsigned)f2bf(acc[rt][6][i]) | ((unsigned)f2bf(acc[rt][7][i]) << 16);
        *(uint4*)&O[(size_t)row * FDIM + l15 * 8] = pk;
      }
    }
  }
  __syncthreads();  // protect Bs against a hypothetical next stage
}

// Aggregation body = R10's k_agg verbatim, blockIdx->vb, pool state in
// per-iteration ring slots (pool_sl/done_sl) so the parking-free epilogue
// survives grid-striding (R15: no end barriers; R16: no hot global atomics).
template <int POOL, int PACKED>
__device__ __forceinline__ void agg_body(
    int vb, int tid, const ushort_t* __restrict__ Hin,
    ushort_t* __restrict__ Hout, const int* __restrict__ rowStart,
    const int* __restrict__ degE, const unsigned* __restrict__ colPacked,
    const float* __restrict__ dis, const float* __restrict__ bias, int n,
    const int* __restrict__ batch, float* __restrict__ partials_blk,
    float* __restrict__ partials_g, float* pool_sl, int* done_sl) {
  int node = vb * 8 + (tid >> 5);
  int lane = tid & 31;  // uint2 index within the 256 B row
  bool act = node < n;
  if (!POOL && !act) return;
  float a0 = 0.f, a1 = 0.f, a2 = 0.f, a3 = 0.f;
  if (act) {
    const uint2* hin = (const uint2*)Hin;  // row stride 32 uint2
    float di = dis[node];
    uint2 su = hin[(size_t)node * 32 + lane];
    float ws = di * di;
    a0 = ws * __uint_as_float(su.x << 16);
    a1 = ws * __uint_as_float(su.x & 0xffff0000u);
    a2 = ws * __uint_as_float(su.y << 16);
    a3 = ws * __uint_as_float(su.y & 0xffff0000u);
    int s0 = rowStart[node], cnt = degE[node];
    const unsigned* __restrict__ cp = colPacked + s0;
    int j = 0;
    int main8 = cnt & ~7;
    if (main8) {
      unsigned pv[8];
#pragma unroll
      for (int k = 0; k < 8; ++k) pv[k] = cp[k];
      for (;;) {
        float dv[8];
        uint2 u[8];
#pragma unroll
        for (int k = 0; k < 8; ++k) {
          unsigned sidx = pv[k] & 0x1ffffu;
          if (!PACKED) dv[k] = dis[(int)sidx];
          u[k] = hin[(size_t)sidx * 32 + lane];
        }
        int jn = j + 8;
        bool more = jn < main8;
        unsigned pn[8];
        if (more) {
#pragma unroll
          for (int k = 0; k < 8; ++k) pn[k] = cp[jn + k];
        }
#pragma unroll
        for (int k = 0; k < 8; ++k) {
          float w = PACKED ? di * __uint_as_float((pv[k] >> 17) << 16) : di * dv[k];
          a0 += w * __uint_as_float(u[k].x << 16);
          a1 += w * __uint_as_float(u[k].x & 0xffff0000u);
          a2 += w * __uint_as_float(u[k].y << 16);
          a3 += w * __uint_as_float(u[k].y & 0xffff0000u);
        }
        j = jn;
        if (!more) break;
#pragma unroll
        for (int k = 0; k < 8; ++k) pv[k] = pn[k];
      }
    }
    if (j + 4 <= cnt) {  // 4-deep tail group
      unsigned pv[4];
#pragma unroll
      for (int k = 0; k < 4; ++k) pv[k] = cp[j + k];
      float dv[4];
      uint2 u[4];
#pragma unroll
      for (int k = 0; k < 4; ++k) {
        unsigned sidx = pv[k] & 0x1ffffu;
        if (!PACKED) dv[k] = dis[(int)sidx];
        u[k] = hin[(size_t)sidx * 32 + lane];
      }
#pragma unroll
      for (int k = 0; k < 4; ++k) {
        float w = PACKED ? di * __uint_as_float((pv[k] >> 17) << 16) : di * dv[k];
        a0 += w * __uint_as_float(u[k].x << 16);
        a1 += w * __uint_as_float(u[k].x & 0xffff0000u);
        a2 += w * __uint_as_float(u[k].y << 16);
        a3 += w * __uint_as_float(u[k].y & 0xffff0000u);
      }
      j += 4;
    }
    for (; j < cnt; ++j) {  // scalar tail (<= 3)
      unsigned pv = cp[j];
      unsigned sidx = pv & 0x1ffffu;
      float w = PACKED ? di * __uint_as_float((pv >> 17) << 16)
                       : di * dis[(int)sidx];
      uint2 u = hin[(size_t)sidx * 32 + lane];
      a0 += w * __uint_as_float(u.x << 16);
      a1 += w * __uint_as_float(u.x & 0xffff0000u);
      a2 += w * __uint_as_float(u.y << 16);
      a3 += w * __uint_as_float(u.y & 0xffff0000u);
    }
    float4 b = ((const float4*)bias)[lane];
    a0 = fmaxf(a0 + b.x, 0.f);
    a1 = fmaxf(a1 + b.y, 0.f);
    a2 = fmaxf(a2 + b.z, 0.f);
    a3 = fmaxf(a3 + b.w, 0.f);
    if (!POOL) {
      uint2 o;
      o.x = (unsigned)f2bf(a0) | ((unsigned)f2bf(a1) << 16);
      o.y = (unsigned)f2bf(a2) | ((unsigned)f2bf(a3) << 16);
      ((uint2*)Hout)[(size_t)node * 32 + lane] = o;
    }
  }
  if (POOL) {
    int base = vb * 8;
    int lastn = min(base + 7, n - 1);
    int g0 = batch[base];
    int sg = (g0 == batch[lastn]) ? g0 : -1;  // uniform across block
    int w = tid >> 6;   // wave id, 0..3
    int wl = tid & 63;
    int pl = wl ^ 32;  // partner lane: same feature slot, other node
    float p0 = __shfl(a0, pl);
    float p1 = __shfl(a1, pl);
    float p2 = __shfl(a2, pl);
    float p3 = __shfl(a3, pl);
    if (sg >= 0) {  // whole block one graph: plain LDS slot, no atomics
      if (wl < 32) {
        float4 v = {a0 + p0, a1 + p1, a2 + p2, a3 + p3};
        *(float4*)&pool_sl[w * FDIM + wl * 4] = v;
      }
    } else {  // boundary block (rare): zero slot + direct global atomics
      if (wl < 32) *(float4*)&pool_sl[w * FDIM + wl * 4] = float4{0.f, 0.f, 0.f, 0.f};
      if (act) {
        int gn = batch[node];
        float* pg = &partials_g[(size_t)gn * FDIM + lane * 4];
        atomicAdd(pg + 0, a0);
        atomicAdd(pg + 1, a1);
        atomicAdd(pg + 2, a2);
        atomicAdd(pg + 3, a3);
      }
    }
    __threadfence_block();  // drain this wave's LDS writes
    int old = 0;
    if (wl == 0) old = atomicAdd(done_sl, 1);
    old = __shfl(old, 0);
    if (old == 3) {  // last of 4 waves: reduce 4 rows, one plain 512B store
      int c = wl * 2;
      float s0v = 0.f, s1v = 0.f;
#pragma unroll
      for (int ww = 0; ww < 4; ++ww) {
        float2 v = *(float2*)&pool_sl[ww * FDIM + c];
        s0v += v.x;
        s1v += v.y;
      }
      *(float2*)&partials_blk[(size_t)vb * FDIM + c] = float2{s0v, s1v};
    }
  }
}

__device__ inline int lower_bound_batch(const int* __restrict__ batch, int n, int g) {
  int lo = 0, hi = n;
  while (lo < hi) {
    int mid = (lo + hi) >> 1;
    if (batch[mid] < g) lo = mid + 1;
    else hi = mid;
  }
  return lo;
}

__device__ __forceinline__ void final_body(int g, int tid,
                                           const float* __restrict__ partials_blk,
                                           const float* __restrict__ partials_g,
                                           const int* __restrict__ batch, int n,
                                           const float* __restrict__ Wc,
                                           const float* __restrict__ bc,
                                           float* __restrict__ out,
                                           float (*red2)[FDIM], int* se,
                                           float* red) {
  if (tid < 2) se[tid] = lower_bound_batch(batch, n, g + tid);
  __syncthreads();
  int s = se[0], e = se[1];
  int f = tid & 127;
  int r = tid >> 7;  // 0..1 (256 threads, 2-way split)
  float acc = (r == 0) ? partials_g[(size_t)g * FDIM + f] : 0.f;
  for (int b = ((s + 7) >> 3) + r; b * 8 < e; b += 2) {
    if (b * 8 + 8 <= e || e >= n) acc += partials_blk[(size_t)b * FDIM + f];
  }
  red2[r][f] = acc;
  __syncthreads();
  if (tid < FDIM) {
    float sv = (red2[0][tid] + red2[1][tid]) / (float)max(e - s, 1);
#pragma unroll
    for (int c = 0; c < 3; ++c) {
      float v = sv * Wc[tid * 3 + c];
#pragma unroll
      for (int off = 1; off < 64; off <<= 1) v += __shfl_xor(v, off);
      if ((tid & 63) == 0) red[(tid >> 6) * 3 + c] = v;
    }
  }
  __syncthreads();
  if (tid < 3) out[g * 3 + tid] = red[tid] + red[3 + tid] + bc[tid];
}

// ---------------- mega kernel: agg1+EDGW | mm2 | agg2 | mm3 | agg3 | final
// R20: 6 serial phases, 5 grid barriers, ONE launch (was 6 launches; the
// ~13us/boundary gap model from the R8->R9 A/B is the target). Grid =
// 1024 = 256 CU x 4 blocks/CU exact residency; launch_bounds(256,4) caps
// VGPR at 128; LDS = 32KB union x 4 = 128KB <= 160KB.
__global__ __launch_bounds__(256, 4) void k_mega(
    ushort_t* __restrict__ h0, ushort_t* __restrict__ h1,
    const int* __restrict__ rowStart, const int* __restrict__ degE,
    unsigned* __restrict__ colPacked, const float* __restrict__ dis,
    const float* __restrict__ b1, const float* __restrict__ b2,
    const float* __restrict__ b3, int n, int e, const int* __restrict__ batch,
    float* __restrict__ partials_blk, float* __restrict__ partials_g,
    const ushort_t* __restrict__ wsw, const float* __restrict__ Wc,
    const float* __restrict__ bc, float* __restrict__ out, int g_count,
    int* __restrict__ bar, int nblk) {
  __shared__ union SMU {
    ushort_t Bs[16384];          // 32 KB mm weight tile
    float pool[16][4][FDIM];     // 32 KB pool ring (<=16 grid-stride iters)
    struct {
      float red2[2][FDIM];
      int se[2];
      float red[6];
    } fin;
  } sm;
  __shared__ int done[16];
  int tid = threadIdx.x;
  int bid = blockIdx.x;
  int aggv = (n + 7) >> 3;
  int mmv = (n + 127) >> 7;
  int ewv = (e + 2047) >> 11;

  // P1: agg1 (dis-gather weights) + EDGW rider packing weights for P3/P5
  for (int vb = bid; vb < aggv + ewv; vb += nblk) {
    if (vb < aggv)
      agg_body<0, 0>(vb, tid, h0, h1, rowStart, degE, colPacked, dis, b1, n,
                     nullptr, nullptr, nullptr, nullptr, nullptr);
    else
      edgw_body(vb - aggv, tid, colPacked, dis, e);
  }
  grid_sync(bar, nblk, 1, bid);
  // P2: mm2 (h1 @ W2 -> h0)
  for (int vb = bid; vb < mmv; vb += nblk)
    mm_body(vb, tid, h1, wsw, h0, n, sm.Bs);
  grid_sync(bar, nblk, 2, bid);
  // P3: agg2 (packed weights)
  for (int vb = bid; vb < aggv; vb += nblk)
    agg_body<0, 1>(vb, tid, h0, h1, rowStart, degE, colPacked, dis, b2, n,
                   nullptr, nullptr, nullptr, nullptr, nullptr);
  grid_sync(bar, nblk, 3, bid);
  // P4: mm3 (h1 @ W3 -> h0)
  for (int vb = bid; vb < mmv; vb += nblk)
    mm_body(vb, tid, h1, wsw + 16384, h0, n, sm.Bs);
  grid_sync(bar, nblk, 4, bid);
  // P5: agg3 + fused mean-pool (ring-slotted, parking-free)
  if (tid < 16) done[tid] = 0;
  __syncthreads();
  {
    int it = 0;
    for (int vb = bid; vb < aggv; vb += nblk, ++it)
      agg_body<1, 1>(vb, tid, h0, nullptr, rowStart, degE, colPacked, dis, b3,
                     n, batch, partials_blk, partials_g, &sm.pool[it][0][0],
                     &done[it]);
  }
  grid_sync(bar, nblk, 5, bid);
  // P6: final classify (one virtual block per graph)
  if (bid < g_count)
    final_body(bid, tid, partials_blk, partials_g, batch, n, Wc, bc, out,
               sm.fin.red2, sm.fin.se, sm.fin.red);
}

// ---------------- host ----------------

extern "C" void kernel_launch(void* const* d_in, const int* in_sizes, int n_in,
                              void* d_out, int out_size, void* d_ws, size_t ws_size,
                              hipStream_t stream) {
  const float* x = (const float*)d_in[0];
  const int* edge = (const int*)d_in[1];
  const int* batch = (const int*)d_in[2];
  const float* W1 = (const float*)d_in[3];
  const float* b1 = (const float*)d_in[4];
  const float* W2 = (const float*)d_in[5];
  const float* b2 = (const float*)d_in[6];
  const float* W3 = (const float*)d_in[7];
  const float* b3 = (const float*)d_in[8];
  const float* Wc = (const float*)d_in[9];
  const float* bc = (const float*)d_in[10];
  float* out = (float*)d_out;

  const int N = in_sizes[0] / FDIM;
  const int E = in_sizes[1] / 2;
  const int G = out_size / 3;
  const int* src = edge;
  const int* dst = edge + E;

  const int NCH = (E + CHUNK - 1) / CHUNK;
  const int NB = (N + (1 << BSHIFT) - 1) >> BSHIFT;

  char* ws = (char*)d_ws;
  size_t off = 0;
  auto carve = [&](size_t bytes) -> void* {
    void* p = ws + off;
    off = (off + bytes + 255) & ~(size_t)255;
    return p;
  };
  int aggb = (N + 7) / 8;
  ushort_t* h0 = (ushort_t*)carve((size_t)N * FDIM * 2);  // row-major bf16
  ushort_t* h1 = (ushort_t*)carve((size_t)N * FDIM * 2);
  unsigned* colPacked = (unsigned*)carve((size_t)E * 4);
  unsigned* binned = (unsigned*)carve((size_t)E * 4);
  int* chunkHist = (int*)carve((size_t)NCH * NB * 4);
  int* chunkOff = (int*)carve((size_t)NCH * NB * 4);
  int* bucketTotal = (int*)carve((size_t)NB * 4);
  int* bucketBase = (int*)carve((size_t)NB * 4);
  int* counter = (int*)carve(256);
  int* bar = (int*)carve(256);  // grid-barrier state (zeroed each iter)
  int* rowStart = (int*)carve((size_t)N * 4);
  int* deg = (int*)carve((size_t)N * 4);
  float* dis = (float*)carve((size_t)N * 4);
  float* partials_g = (float*)carve((size_t)G * FDIM * 4);    // boundary accum
  float* partials_blk = (float*)carve((size_t)aggb * FDIM * 4);  // per-block rows
  ushort_t* wsw = (ushort_t*)carve((size_t)2 * 16384 * 2);  // swizzled W2,W3
  (void)n_in;
  (void)ws_size;

  int mmb = (N + 127) / 128;
  // front: mm1 (x@W1, inline W1 conversion) + hist + W2/W3 prep + zeroing
  k_front<<<mmb + NCH + 3, 256, 0, stream>>>(x, W1, W2, W3, h0, N, mmb, dst, E, NB,
                                             chunkHist, NCH, wsw, counter,
                                             partials_g, G, bar);
  k_scan1<<<NB, 512, 0, stream>>>(chunkHist, NCH, NB, chunkOff, bucketTotal,
                                  bucketBase, counter);
  k_bin<<<NCH, 256, 0, stream>>>(src, dst, E, NB, chunkHist, chunkOff, bucketBase,
                                 binned);
  k_fill2<<<NB, 256, 0, stream>>>(binned, bucketBase, bucketTotal, N, rowStart, deg,
                                  dis, colPacked);
  // whole layer chain + pooling + classify in ONE launch (5 grid barriers)
  k_mega<<<GRIDB, 256, 0, stream>>>(h0, h1, rowStart, deg, colPacked, dis, b1, b2,
                                    b3, N, E, batch, partials_blk, partials_g, wsw,
                                    Wc, bc, out, G, bar, GRIDB);
}

// Round 12
// 417.958 us; speedup vs baseline: 2.9300x; 2.9300x over previous
//
#include <hip/hip_runtime.h>
#include <cstdint>
#include <cstddef>

#define FDIM 128
#define CHUNK 4096   // edges per binning chunk
#define BSHIFT 8     // 256 nodes per bucket
#define BMASK 255
#define MAXB 512     // max buckets supported (N <= 131072)

typedef unsigned short ushort_t;
typedef __attribute__((ext_vector_type(8))) short short8;   // 8 bf16 (4 VGPRs)
typedef __attribute__((ext_vector_type(4))) float floatx4;  // MFMA C/D

// bf16 helpers (bit-level, RTN-even).
__device__ inline ushort_t f2bf(float f) {
  unsigned u = __float_as_uint(f);
  u += 0x7fffu + ((u >> 16) & 1u);
  return (ushort_t)(u >> 16);
}
__device__ inline float bf2f(ushort_t h) {
  return __uint_as_float((unsigned)h << 16);
}

// R21 NOTE: the R11 single-launch mega-kernel (5 device grid barriers) ran
// 1106us with NOMINAL traffic -- ~160us per barrier. Mechanism: per-block
// __threadfence release/acquire = full L2 writeback/invalidate on every
// XCD, 1024 blocks x 2 fences x 5 barriers, vs once-in-HW per kernel
// boundary. Grid-wide phase barriers on non-coherent XCDs are only viable
// with per-XCD cache maintenance (s_getreg XCC_ID + buffer_wbl2) -- not
// attempted; split launches are the verified design.

// ---------------- front kernel: mm1 (x@W1) + hist + W-prep + zero --------
// R18: launch overhead is the #2 cost; mm1 has no dep on the CSR build so
// it rides the hist launch. Blocks [0,mmb)=mm1 w/ inline W1 conversion;
// [mmb,mmb+nch)=chunk hist; +0=W2 prep & counter; +1=W3 prep; +2=zero.
__global__ __launch_bounds__(256) void k_front(
    const float* __restrict__ x, const float* __restrict__ W1,
    const float* __restrict__ W2, const float* __restrict__ W3,
    ushort_t* __restrict__ h0, int n, int mmb,
    const int* __restrict__ dst, int e, int nb,
    int* __restrict__ chunkHist, int nch,
    ushort_t* __restrict__ wsw, int* __restrict__ counter,
    float* __restrict__ partials_g, int g_count) {
  __shared__ ushort_t Bs[16384];  // 32 KB (hist path aliases first 2 KB)
  int tid = threadIdx.x;
  int bid = blockIdx.x;
  if (bid >= mmb) {
    int r = bid - mmb;
    if (r < nch) {  // per-chunk dst-bucket histogram (R14: keep bucketed)
      int* h = (int*)Bs;
      int base = r * CHUNK;
      int end = min(base + CHUNK, e);
      for (int i = tid; i < nb; i += 256) h[i] = 0;
      __syncthreads();
      for (int i = base + tid; i < end; i += 256)
        atomicAdd(&h[dst[i] >> BSHIFT], 1);
      __syncthreads();
      for (int b = tid; b < nb; b += 256)
        chunkHist[(size_t)r * nb + b] = h[b];
      return;
    }
    int b = r - nch;
    if (b == 2) {  // zero boundary-pool accumulator (G x 128 f32)
      for (int i = tid; i < g_count * FDIM; i += 256) partials_g[i] = 0.f;
      return;
    }
    if (b == 0 && tid == 0) *counter = 0;  // for scan1's atomic bump
    // W prep (W2,W3): fp32 -> bf16, B-fragment order (slot (ct,lane&15)
    // holds TRUE column (lane&15)*8+ct -> coalesced uint4 C-stores).
    const float* W = (b == 0) ? W2 : W3;
    ushort_t* o = wsw + (size_t)b * 16384;
    for (int idx = tid; idx < 16384; idx += 256) {
      int j = idx & 7;
      int lane = (idx >> 3) & 63;
      int ct = (idx >> 9) & 7;
      int kc = idx >> 12;
      int k = kc * 32 + (lane >> 4) * 8 + j;
      int col = (lane & 15) * 8 + ct;
      o[idx] = f2bf(W[k * FDIM + col]);
    }
    return;
  }
  // ---- mm1: fp32 x @ W1 -> h0 bf16; W1 converted inline during staging.
  for (int q = tid; q < 2048; q += 256) {
    int lane = q & 63;
    int ct = (q >> 6) & 7;
    int kc = q >> 9;
    int col = (lane & 15) * 8 + ct;
    int kb = kc * 32 + (lane >> 4) * 8;
    unsigned t0 = f2bf(W1[(kb + 0) * FDIM + col]);
    unsigned t1 = f2bf(W1[(kb + 1) * FDIM + col]);
    unsigned t2 = f2bf(W1[(kb + 2) * FDIM + col]);
    unsigned t3 = f2bf(W1[(kb + 3) * FDIM + col]);
    unsigned t4 = f2bf(W1[(kb + 4) * FDIM + col]);
    unsigned t5 = f2bf(W1[(kb + 5) * FDIM + col]);
    unsigned t6 = f2bf(W1[(kb + 6) * FDIM + col]);
    unsigned t7 = f2bf(W1[(kb + 7) * FDIM + col]);
    uint4 pk;
    pk.x = t0 | (t1 << 16);
    pk.y = t2 | (t3 << 16);
    pk.z = t4 | (t5 << 16);
    pk.w = t6 | (t7 << 16);
    ((uint4*)Bs)[q] = pk;
  }
  __syncthreads();

  int w = tid >> 6;
  int lane = tid & 63;
  int quad = lane >> 4;
  int l15 = lane & 15;
  int rb = bid * 128 + w * 32;
  int row0 = rb + l15;
  int row1 = rb + 16 + l15;
  bool v0 = row0 < n, v1 = row1 < n;

  floatx4 acc[2][8];
#pragma unroll
  for (int rt = 0; rt < 2; ++rt)
#pragma unroll
    for (int ct = 0; ct < 8; ++ct) acc[rt][ct] = floatx4{0.f, 0.f, 0.f, 0.f};

#pragma unroll
  for (int kc = 0; kc < 4; ++kc) {
    int k0 = kc * 32 + quad * 8;
    short8 a0 = short8{0, 0, 0, 0, 0, 0, 0, 0};
    short8 a1 = short8{0, 0, 0, 0, 0, 0, 0, 0};
    if (v0) {
      float4 f0 = *(const float4*)&x[(size_t)row0 * FDIM + k0];
      float4 f1 = *(const float4*)&x[(size_t)row0 * FDIM + k0 + 4];
      a0 = short8{(short)f2bf(f0.x), (short)f2bf(f0.y), (short)f2bf(f0.z),
                  (short)f2bf(f0.w), (short)f2bf(f1.x), (short)f2bf(f1.y),
                  (short)f2bf(f1.z), (short)f2bf(f1.w)};
    }
    if (v1) {
      float4 f0 = *(const float4*)&x[(size_t)row1 * FDIM + k0];
      float4 f1 = *(const float4*)&x[(size_t)row1 * FDIM + k0 + 4];
      a1 = short8{(short)f2bf(f0.x), (short)f2bf(f0.y), (short)f2bf(f0.z),
                  (short)f2bf(f0.w), (short)f2bf(f1.x), (short)f2bf(f1.y),
                  (short)f2bf(f1.z), (short)f2bf(f1.w)};
    }
#pragma unroll
    for (int ct = 0; ct < 8; ++ct) {
      short8 bf = *(const short8*)&Bs[((kc * 8 + ct) * 64 + lane) * 8];
      acc[0][ct] = __builtin_amdgcn_mfma_f32_16x16x32_bf16(a0, bf, acc[0][ct], 0, 0, 0);
      acc[1][ct] = __builtin_amdgcn_mfma_f32_16x16x32_bf16(a1, bf, acc[1][ct], 0, 0, 0);
    }
  }
#pragma unroll
  for (int rt = 0; rt < 2; ++rt) {
#pragma unroll
    for (int i = 0; i < 4; ++i) {
      int row = rb + rt * 16 + quad * 4 + i;
      if (row < n) {
        uint4 pk;
        pk.x = (unsigned)f2bf(acc[rt][0][i]) | ((unsigned)f2bf(acc[rt][1][i]) << 16);
        pk.y = (unsigned)f2bf(acc[rt][2][i]) | ((unsigned)f2bf(acc[rt][3][i]) << 16);
        pk.z = (unsigned)f2bf(acc[rt][4][i]) | ((unsigned)f2bf(acc[rt][5][i]) << 16);
        pk.w = (unsigned)f2bf(acc[rt][6][i]) | ((unsigned)f2bf(acc[rt][7][i]) << 16);
        *(uint4*)&h0[(size_t)row * FDIM + l15 * 8] = pk;
      }
    }
  }
}

// Per-bucket scan over the chunk axis; bucket base atomic-bump allocated
// (disjoint segments, order-free -- validated R10).
__global__ __launch_bounds__(512) void k_scan1(const int* __restrict__ chunkHist,
                                               int nchunks, int nb,
                                               int* __restrict__ chunkOff,
                                               int* __restrict__ bucketTotal,
                                               int* __restrict__ bucketBase,
                                               int* __restrict__ counter) {
  __shared__ int sb[512];
  int b = blockIdx.x;
  int t = threadIdx.x;
  int base = 0;
  for (int c0 = 0; c0 < nchunks; c0 += 512) {
    int c = c0 + t;
    int v = (c < nchunks) ? chunkHist[(size_t)c * nb + b] : 0;
    int x = v;
    sb[t] = x;
    __syncthreads();
    for (int off = 1; off < 512; off <<= 1) {
      int y = (t >= off) ? sb[t - off] : 0;
      __syncthreads();
      x += y;
      sb[t] = x;
      __syncthreads();
    }
    if (c < nchunks) chunkOff[(size_t)c * nb + b] = base + x - v;
    int tileTot = sb[511];
    __syncthreads();
    base += tileTot;
  }
  if (t == 0) {
    bucketTotal[b] = base;
    bucketBase[b] = atomicAdd(counter, base);
  }
}

__global__ __launch_bounds__(256) void k_bin(const int* __restrict__ src,
                                             const int* __restrict__ dst, int e, int nb,
                                             const int* __restrict__ chunkHist,
                                             const int* __restrict__ chunkOff,
                                             const int* __restrict__ bucketBase,
                                             unsigned* __restrict__ binned) {
  __shared__ unsigned sortedL[CHUNK];
  __shared__ int gtarget[CHUNK];
  __shared__ int lbase[MAXB], lcur[MAXB], gbase[MAXB];
  __shared__ int stmp[256];
  int c = blockIdx.x;
  int base = c * CHUNK;
  int end = min(base + CHUNK, e);
  for (int i = threadIdx.x; i < nb; i += 256) {
    lbase[i] = chunkHist[(size_t)c * nb + i];  // temp: counts
    gbase[i] = bucketBase[i] + chunkOff[(size_t)c * nb + i];
  }
  __syncthreads();
  int carry = 0;
  for (int i0 = 0; i0 < nb; i0 += 256) {
    int i = i0 + threadIdx.x;
    int v = (i < nb) ? lbase[i] : 0;
    int x = v;
    stmp[threadIdx.x] = x;
    __syncthreads();
    for (int off = 1; off < 256; off <<= 1) {
      int y = (threadIdx.x >= off) ? stmp[threadIdx.x - off] : 0;
      __syncthreads();
      x += y;
      stmp[threadIdx.x] = x;
      __syncthreads();
    }
    if (i < nb) lbase[i] = carry + x - v;
    int tileTot = stmp[255];
    __syncthreads();
    carry += tileTot;
  }
  for (int i = threadIdx.x; i < nb; i += 256) lcur[i] = lbase[i];
  __syncthreads();
  for (int i = base + threadIdx.x; i < end; i += 256) {
    int d = dst[i];
    int sv = src[i];
    int b = d >> BSHIFT;
    int slot = atomicAdd(&lcur[b], 1);
    sortedL[slot] = ((unsigned)sv << BSHIFT) | (unsigned)(d & BMASK);
    gtarget[slot] = gbase[b] + (slot - lbase[b]);
  }
  __syncthreads();
  for (int i = threadIdx.x; i < end - base; i += 256)
    binned[gtarget[i]] = sortedL[i];
}

// One block per bucket: per-node CSR rows in the bucket's private window.
// colPacked = pure src here; agg1's rider ORs in bf16(dis[src])<<17.
__global__ __launch_bounds__(256) void k_fill2(const unsigned* __restrict__ binned,
                                               const int* __restrict__ bucketBase,
                                               const int* __restrict__ bucketTotal,
                                               int n,
                                               int* __restrict__ rowStart,
                                               int* __restrict__ deg,
                                               float* __restrict__ dis,
                                               unsigned* __restrict__ colPacked) {
  __shared__ int h[256], sb[256], cur[256];
  int b = blockIdx.x;
  int s0 = bucketBase[b], s1 = s0 + bucketTotal[b];
  int nodeBase = b << BSHIFT;
  int t = threadIdx.x;
  h[t] = 0;
  __syncthreads();
  for (int i = s0 + t; i < s1; i += 256) atomicAdd(&h[binned[i] & BMASK], 1);
  __syncthreads();
  int v = h[t];
  int x = v;
  sb[t] = x;
  __syncthreads();
  for (int off = 1; off < 256; off <<= 1) {
    int y = (t >= off) ? sb[t - off] : 0;
    __syncthreads();
    x += y;
    sb[t] = x;
    __syncthreads();
  }
  int start = s0 + x - v;
  cur[t] = start;
  int node = nodeBase + t;
  if (node < n) {
    rowStart[node] = start;
    deg[node] = v;
    dis[node] = rsqrtf((float)(v + 1));  // +1 self-loop
  }
  __syncthreads();
  for (int i = s0 + t; i < s1; i += 256) {
    unsigned en = binned[i];
    int slot = atomicAdd(&cur[en & BMASK], 1);
    colPacked[slot] = en >> BSHIFT;  // pure src (< 2^17)
  }
}

// ---------------- MFMA matmul, bf16 input (layers 2,3) --------------------
__global__ __launch_bounds__(256) void k_mm(const ushort_t* __restrict__ Ain,
                                            const ushort_t* __restrict__ Wsw,
                                            ushort_t* __restrict__ O, int n) {
  __shared__ ushort_t Bs[16384];  // 32 KB
  int tid = threadIdx.x;
  for (int q = tid; q < 2048; q += 256)
    ((uint4*)Bs)[q] = ((const uint4*)Wsw)[q];
  __syncthreads();

  int w = tid >> 6;
  int lane = tid & 63;
  int quad = lane >> 4;
  int l15 = lane & 15;
  int rb = blockIdx.x * 128 + w * 32;

  int row0 = rb + l15;
  int row1 = rb + 16 + l15;
  bool v0 = row0 < n, v1 = row1 < n;

  floatx4 acc[2][8];
#pragma unroll
  for (int rt = 0; rt < 2; ++rt)
#pragma unroll
    for (int ct = 0; ct < 8; ++ct) acc[rt][ct] = floatx4{0.f, 0.f, 0.f, 0.f};

#pragma unroll
  for (int kc = 0; kc < 4; ++kc) {
    int k0 = kc * 32 + quad * 8;
    short8 a0 = short8{0, 0, 0, 0, 0, 0, 0, 0};
    short8 a1 = short8{0, 0, 0, 0, 0, 0, 0, 0};
    if (v0) a0 = *(const short8*)&Ain[(size_t)row0 * FDIM + k0];
    if (v1) a1 = *(const short8*)&Ain[(size_t)row1 * FDIM + k0];
#pragma unroll
    for (int ct = 0; ct < 8; ++ct) {
      short8 bf = *(const short8*)&Bs[((kc * 8 + ct) * 64 + lane) * 8];
      acc[0][ct] = __builtin_amdgcn_mfma_f32_16x16x32_bf16(a0, bf, acc[0][ct], 0, 0, 0);
      acc[1][ct] = __builtin_amdgcn_mfma_f32_16x16x32_bf16(a1, bf, acc[1][ct], 0, 0, 0);
    }
  }

#pragma unroll
  for (int rt = 0; rt < 2; ++rt) {
#pragma unroll
    for (int i = 0; i < 4; ++i) {
      int row = rb + rt * 16 + quad * 4 + i;
      if (row < n) {
        uint4 pk;
        pk.x = (unsigned)f2bf(acc[rt][0][i]) | ((unsigned)f2bf(acc[rt][1][i]) << 16);
        pk.y = (unsigned)f2bf(acc[rt][2][i]) | ((unsigned)f2bf(acc[rt][3][i]) << 16);
        pk.z = (unsigned)f2bf(acc[rt][4][i]) | ((unsigned)f2bf(acc[rt][5][i]) << 16);
        pk.w = (unsigned)f2bf(acc[rt][6][i]) | ((unsigned)f2bf(acc[rt][7][i]) << 16);
        *(uint4*)&O[(size_t)row * FDIM + l15 * 8] = pk;
      }
    }
  }
}

// ---------------- aggregation (pull) + bias + ReLU [+ pool] [+ EDGW] ------
// 2 nodes per wave; 4 waves/block. PACKED selects weight source: layer 1
// (PACKED=0) reads dis[src] (weights can't exist pre-fill2) and carries
// EDGW rider blocks that pack colPacked[i] = src | bf16(dis)<<17 for
// layers 2-3 (PACKED=1 -- R9 showed the dis gather costs ~6us/agg).
// R21: rider blocks dispatch FIRST (blockIdx < ewv) so the ~5us streaming
// pack retires while the agg wave-pool fills, instead of trailing the agg
// tail. Safety: rider's full-word store preserves low 17 bits and both
// readers mask 0x1ffff, so any interleaving is valid (R10-validated).
// POOL=1: no h-write; shfl pair-combine -> LDS row/wave -> done-counter,
// waves exit (no end-barrier parking R15, no hot global atomics R16);
// last wave (old==3) stores 512B to partials_blk. Boundary blocks use
// partials_g atomics.
template <int POOL, int PACKED, int EDGW>
__global__ __launch_bounds__(256) void k_agg(const ushort_t* __restrict__ Hin,
                                             ushort_t* __restrict__ Hout,
                                             const int* __restrict__ rowStart,
                                             const int* __restrict__ degE,
                                             unsigned* __restrict__ colPacked,
                                             const float* __restrict__ dis,
                                             const float* __restrict__ bias, int n,
                                             int e,
                                             const int* __restrict__ batch,
                                             float* __restrict__ partials_blk,
                                             float* __restrict__ partials_g) {
  int tid = threadIdx.x;
  int ewv = EDGW ? ((e + 2047) >> 11) : 0;
  if (EDGW && blockIdx.x < (unsigned)ewv) {  // rider blocks first (R21)
    int base = blockIdx.x * 2048 + tid;
#pragma unroll
    for (int k = 0; k < 8; ++k) {
      int i = base + k * 256;
      if (i < e) {
        unsigned p = colPacked[i] & 0x1ffffu;
        colPacked[i] = p | ((unsigned)f2bf(dis[p]) << 17);
      }
    }
    return;
  }
  int vb = blockIdx.x - ewv;
  __shared__ float pool_s[POOL ? 4 * FDIM : 4];  // one row per wave
  __shared__ int done;
  if (POOL) {  // init counter at START: barrier here has zero parking cost
    if (tid == 0) done = 0;
    __syncthreads();
  }
  int node = vb * 8 + (tid >> 5);
  int lane = tid & 31;  // uint2 index within the 256 B row
  bool act = node < n;
  if (!POOL && !act) return;
  float a0 = 0.f, a1 = 0.f, a2 = 0.f, a3 = 0.f;
  if (act) {
    const uint2* hin = (const uint2*)Hin;  // row stride 32 uint2
    float di = dis[node];
    uint2 su = hin[(size_t)node * 32 + lane];
    float ws = di * di;
    a0 = ws * __uint_as_float(su.x << 16);
    a1 = ws * __uint_as_float(su.x & 0xffff0000u);
    a2 = ws * __uint_as_float(su.y << 16);
    a3 = ws * __uint_as_float(su.y & 0xffff0000u);
    int s0 = rowStart[node], cnt = degE[node];
    const unsigned* __restrict__ cp = colPacked + s0;

    int j = 0;
    int main8 = cnt & ~7;
    if (main8) {
      unsigned pv[8];
#pragma unroll
      for (int k = 0; k < 8; ++k) pv[k] = cp[k];
      for (;;) {
        float dv[8];
        uint2 u[8];
#pragma unroll
        for (int k = 0; k < 8; ++k) {
          unsigned sidx = pv[k] & 0x1ffffu;
          if (!PACKED) dv[k] = dis[(int)sidx];
          u[k] = hin[(size_t)sidx * 32 + lane];
        }
        int jn = j + 8;
        bool more = jn < main8;
        unsigned pn[8];
        if (more) {
#pragma unroll
          for (int k = 0; k < 8; ++k) pn[k] = cp[jn + k];
        }
#pragma unroll
        for (int k = 0; k < 8; ++k) {
          float w = PACKED ? di * __uint_as_float((pv[k] >> 17) << 16)
                           : di * dv[k];
          a0 += w * __uint_as_float(u[k].x << 16);
          a1 += w * __uint_as_float(u[k].x & 0xffff0000u);
          a2 += w * __uint_as_float(u[k].y << 16);
          a3 += w * __uint_as_float(u[k].y & 0xffff0000u);
        }
        j = jn;
        if (!more) break;
#pragma unroll
        for (int k = 0; k < 8; ++k) pv[k] = pn[k];
      }
    }
    if (j + 4 <= cnt) {  // 4-deep tail group
      unsigned pv[4];
#pragma unroll
      for (int k = 0; k < 4; ++k) pv[k] = cp[j + k];
      float dv[4];
      uint2 u[4];
#pragma unroll
      for (int k = 0; k < 4; ++k) {
        unsigned sidx = pv[k] & 0x1ffffu;
        if (!PACKED) dv[k] = dis[(int)sidx];
        u[k] = hin[(size_t)sidx * 32 + lane];
      }
#pragma unroll
      for (int k = 0; k < 4; ++k) {
        float w = PACKED ? di * __uint_as_float((pv[k] >> 17) << 16)
                         : di * dv[k];
        a0 += w * __uint_as_float(u[k].x << 16);
        a1 += w * __uint_as_float(u[k].x & 0xffff0000u);
        a2 += w * __uint_as_float(u[k].y << 16);
        a3 += w * __uint_as_float(u[k].y & 0xffff0000u);
      }
      j += 4;
    }
    for (; j < cnt; ++j) {  // scalar tail (<= 3)
      unsigned pv = cp[j];
      unsigned sidx = pv & 0x1ffffu;
      float w = PACKED ? di * __uint_as_float((pv >> 17) << 16)
                       : di * dis[(int)sidx];
      uint2 u = hin[(size_t)sidx * 32 + lane];
      a0 += w * __uint_as_float(u.x << 16);
      a1 += w * __uint_as_float(u.x & 0xffff0000u);
      a2 += w * __uint_as_float(u.y << 16);
      a3 += w * __uint_as_float(u.y & 0xffff0000u);
    }
    float4 b = ((const float4*)bias)[lane];
    a0 = fmaxf(a0 + b.x, 0.f);
    a1 = fmaxf(a1 + b.y, 0.f);
    a2 = fmaxf(a2 + b.z, 0.f);
    a3 = fmaxf(a3 + b.w, 0.f);
    if (!POOL) {
      uint2 o;
      o.x = (unsigned)f2bf(a0) | ((unsigned)f2bf(a1) << 16);
      o.y = (unsigned)f2bf(a2) | ((unsigned)f2bf(a3) << 16);
      ((uint2*)Hout)[(size_t)node * 32 + lane] = o;
    }
  }
  if (POOL) {
    int base = vb * 8;
    int lastn = min(base + 7, n - 1);
    int g0 = batch[base];
    int sg = (g0 == batch[lastn]) ? g0 : -1;  // uniform across block
    int w = tid >> 6;   // wave id, 0..3
    int wl = tid & 63;
    int pl = wl ^ 32;  // partner lane: same feature slot, other node
    float p0 = __shfl(a0, pl);
    float p1 = __shfl(a1, pl);
    float p2 = __shfl(a2, pl);
    float p3 = __shfl(a3, pl);
    if (sg >= 0) {  // whole block one graph: plain LDS slot, no atomics
      if (wl < 32) {
        float4 v = {a0 + p0, a1 + p1, a2 + p2, a3 + p3};
        *(float4*)&pool_s[w * FDIM + wl * 4] = v;
      }
    } else {  // boundary block (rare): zero slot + direct global atomics
      if (wl < 32) *(float4*)&pool_s[w * FDIM + wl * 4] = float4{0.f, 0.f, 0.f, 0.f};
      if (act) {
        int gn = batch[node];
        float* pg = &partials_g[(size_t)gn * FDIM + lane * 4];
        atomicAdd(pg + 0, a0);
        atomicAdd(pg + 1, a1);
        atomicAdd(pg + 2, a2);
        atomicAdd(pg + 3, a3);
      }
    }
    __threadfence_block();  // drain this wave's LDS writes
    int old = 0;
    if (wl == 0) old = atomicAdd(&done, 1);
    old = __shfl(old, 0);
    if (old == 3) {  // last of 4 waves: reduce 4 rows, one plain 512B store
      int c = wl * 2;
      float s0 = 0.f, s1 = 0.f;
#pragma unroll
      for (int ww = 0; ww < 4; ++ww) {
        float2 v = *(float2*)&pool_s[ww * FDIM + c];
        s0 += v.x;
        s1 += v.y;
      }
      *(float2*)&partials_blk[(size_t)vb * FDIM + c] = float2{s0, s1};
    }
    // non-last waves exit immediately -> no barrier parking
  }
}

// ---------------- final classify ------------------------------------------

__device__ inline int lower_bound_batch(const int* __restrict__ batch, int n, int g) {
  int lo = 0, hi = n;
  while (lo < hi) {
    int mid = (lo + hi) >> 1;
    if (batch[mid] < g) lo = mid + 1;
    else hi = mid;
  }
  return lo;
}

// One block per graph, 512 threads: 4-way parallel reduce over the graph's
// ~195 block partials + boundary accumulator; mean; classify via shuffles.
// Containment mirrors k_agg routing: block b iff 8b>=s && (8b+8<=e || e==n).
__global__ __launch_bounds__(512) void k_final(const float* __restrict__ partials_blk,
                                               const float* __restrict__ partials_g,
                                               const int* __restrict__ batch, int n,
                                               const float* __restrict__ Wc,
                                               const float* __restrict__ bc,
                                               float* __restrict__ out, int g_count) {
  __shared__ float red2[4][FDIM];
  __shared__ int se[2];
  __shared__ float red[6];  // 2 waves x 3 classes
  int t = threadIdx.x;
  int f = t & 127;
  int r = t >> 7;  // 0..3
  int g = blockIdx.x;
  if (t < 2) se[t] = lower_bound_batch(batch, n, g + t);
  __syncthreads();
  int s = se[0], e = se[1];
  float acc = (r == 0) ? partials_g[(size_t)g * FDIM + f] : 0.f;
  for (int b = ((s + 7) >> 3) + r; b * 8 < e; b += 4) {
    if (b * 8 + 8 <= e || e >= n)
      acc += partials_blk[(size_t)b * FDIM + f];
  }
  red2[r][f] = acc;
  __syncthreads();
  if (t < FDIM) {
    float sv = (red2[0][t] + red2[1][t] + red2[2][t] + red2[3][t]) /
               (float)max(e - s, 1);
#pragma unroll
    for (int c = 0; c < 3; ++c) {
      float v = sv * Wc[t * 3 + c];
#pragma unroll
      for (int off = 1; off < 64; off <<= 1) v += __shfl_xor(v, off);
      if ((t & 63) == 0) red[(t >> 6) * 3 + c] = v;
    }
  }
  __syncthreads();
  if (t < 3) out[g * 3 + t] = red[t] + red[3 + t] + bc[t];
}

// ---------------- host ----------------

extern "C" void kernel_launch(void* const* d_in, const int* in_sizes, int n_in,
                              void* d_out, int out_size, void* d_ws, size_t ws_size,
                              hipStream_t stream) {
  const float* x = (const float*)d_in[0];
  const int* edge = (const int*)d_in[1];
  const int* batch = (const int*)d_in[2];
  const float* W1 = (const float*)d_in[3];
  const float* b1 = (const float*)d_in[4];
  const float* W2 = (const float*)d_in[5];
  const float* b2 = (const float*)d_in[6];
  const float* W3 = (const float*)d_in[7];
  const float* b3 = (const float*)d_in[8];
  const float* Wc = (const float*)d_in[9];
  const float* bc = (const float*)d_in[10];
  float* out = (float*)d_out;

  const int N = in_sizes[0] / FDIM;
  const int E = in_sizes[1] / 2;
  const int G = out_size / 3;
  const int* src = edge;
  const int* dst = edge + E;

  const int NCH = (E + CHUNK - 1) / CHUNK;
  const int NB = (N + (1 << BSHIFT) - 1) >> BSHIFT;

  char* ws = (char*)d_ws;
  size_t off = 0;
  auto carve = [&](size_t bytes) -> void* {
    void* p = ws + off;
    off = (off + bytes + 255) & ~(size_t)255;
    return p;
  };
  int aggb = (N + 7) / 8;
  int ewb = (E + 2047) / 2048;
  ushort_t* h0 = (ushort_t*)carve((size_t)N * FDIM * 2);  // row-major bf16
  ushort_t* h1 = (ushort_t*)carve((size_t)N * FDIM * 2);
  unsigned* colPacked = (unsigned*)carve((size_t)E * 4);
  unsigned* binned = (unsigned*)carve((size_t)E * 4);
  int* chunkHist = (int*)carve((size_t)NCH * NB * 4);
  int* chunkOff = (int*)carve((size_t)NCH * NB * 4);
  int* bucketTotal = (int*)carve((size_t)NB * 4);
  int* bucketBase = (int*)carve((size_t)NB * 4);
  int* counter = (int*)carve(256);
  int* rowStart = (int*)carve((size_t)N * 4);
  int* deg = (int*)carve((size_t)N * 4);
  float* dis = (float*)carve((size_t)N * 4);
  float* partials_g = (float*)carve((size_t)G * FDIM * 4);    // boundary accum
  float* partials_blk = (float*)carve((size_t)aggb * FDIM * 4);  // per-block rows
  ushort_t* wsw = (ushort_t*)carve((size_t)2 * 16384 * 2);  // swizzled W2,W3
  (void)n_in;
  (void)ws_size;

  int mmb = (N + 127) / 128;
  // front: mm1 (x@W1, inline W1 conversion) + hist + W2/W3 prep + zeroing
  k_front<<<mmb + NCH + 3, 256, 0, stream>>>(x, W1, W2, W3, h0, N, mmb, dst, E, NB,
                                             chunkHist, NCH, wsw, counter,
                                             partials_g, G);
  k_scan1<<<NB, 512, 0, stream>>>(chunkHist, NCH, NB, chunkOff, bucketTotal,
                                  bucketBase, counter);
  k_bin<<<NCH, 256, 0, stream>>>(src, dst, E, NB, chunkHist, chunkOff, bucketBase,
                                 binned);
  k_fill2<<<NB, 256, 0, stream>>>(binned, bucketBase, bucketTotal, N, rowStart, deg,
                                  dis, colPacked);

  // layer 1 agg (reads dis[src]) + EDGW rider (dispatched first) packing
  // weights for layers 2-3
  k_agg<0, 0, 1><<<ewb + aggb, 256, 0, stream>>>(h0, h1, rowStart, deg, colPacked,
                                                 dis, b1, N, E, nullptr, nullptr,
                                                 nullptr);
  k_mm<<<mmb, 256, 0, stream>>>(h1, wsw, h0, N);
  k_agg<0, 1, 0><<<aggb, 256, 0, stream>>>(h0, h1, rowStart, deg, colPacked, dis,
                                           b2, N, E, nullptr, nullptr, nullptr);
  k_mm<<<mmb, 256, 0, stream>>>(h1, wsw + 16384, h0, N);
  // layer 3: fused mean-pool, atomic-free/parking-free epilogue
  k_agg<1, 1, 0><<<aggb, 256, 0, stream>>>(h0, h1, rowStart, deg, colPacked, dis,
                                           b3, N, E, batch, partials_blk,
                                           partials_g);

  k_final<<<G, 512, 0, stream>>>(partials_blk, partials_g, batch, N, Wc, bc, out, G);
}